// Round 3
// 984.091 us; speedup vs baseline: 1.5026x; 1.5026x over previous
//
#include <hip/hip_runtime.h>
#include <math.h>

// SwinTransformerBlockV2, B=8 H=W=256 C=64, 4 heads, 4x4 windows, shift 8.
// Shift 8 is a multiple of window 4 -> roll+partition == plain partition
// (permuted window ids), and mask region boundaries are window-aligned ->
// mask == 0. Hence plain per-window attention on the natural partition.
//
// R3 structure: attn kernel is the proven scalar kernel (R0, absmax 0.031)
// with ONLY the QKV phase replaced by MFMA double-bf16 (hi+lo):
// a*b ~= ah*bh + ah*bl + al*bh. Everything downstream (normalize, softmax,
// PV, scalar proj, LN1, residual, store) is verbatim the passing version.
// MLP runs on MFMA hi+lo as before (proven).

#define LDX 68
#define LDQ 17

typedef __attribute__((ext_vector_type(8))) short bf16x8;
typedef __attribute__((ext_vector_type(4))) float f32x4;

__device__ inline unsigned short f2bf(float f) {
  unsigned u = __builtin_bit_cast(unsigned, f);
  u = (u + 0x7FFFu + ((u >> 16) & 1u)) >> 16;
  return (unsigned short)u;
}
__device__ inline float bf2f(unsigned short h) {
  return __builtin_bit_cast(float, ((unsigned)h) << 16);
}

// split v into hi (bf16) + lo (bf16 of residual)
__device__ inline void split1(float v, unsigned short& h, unsigned short& l) {
  h = f2bf(v);
  l = f2bf(v - bf2f(h));
}

// load 8 consecutive floats at p, split into hi/lo bf16x8 fragments
__device__ inline void splitload8(const float* p, bf16x8& h8, bf16x8& l8) {
  float4 a = *(const float4*)p;
  float4 b = *(const float4*)(p + 4);
  float v[8] = {a.x, a.y, a.z, a.w, b.x, b.y, b.z, b.w};
#pragma unroll
  for (int r = 0; r < 8; ++r) {
    unsigned short hh, ll;
    split1(v[r], hh, ll);
    h8[r] = (short)hh;
    l8[r] = (short)ll;
  }
}

// ---------------- Kernel A: CPB bias table + logit scales ----------------
__global__ __launch_bounds__(256) void cpb_bias_kernel(
    const float* __restrict__ w1, const float* __restrict__ b1,
    const float* __restrict__ w2, const float* __restrict__ ls,
    float* __restrict__ bias_out /*4*16*16*/, float* __restrict__ scale_out /*4*/) {
  __shared__ float table[196];  // [49][4]
  int tid = threadIdx.x;
  if (tid < 196) {
    int r = tid >> 2, h = tid & 3;
    int ih = r / 7, iw = r % 7;
    float t0 = (float)(ih - 3) * (8.0f / 3.0f);
    float t1 = (float)(iw - 3) * (8.0f / 3.0f);
    float c0 = copysignf(log2f(fabsf(t0) + 1.0f) * (1.0f / 3.0f), t0);
    float c1 = copysignf(log2f(fabsf(t1) + 1.0f) * (1.0f / 3.0f), t1);
    float acc = 0.f;
    for (int k = 0; k < 512; ++k) {
      float hid = c0 * w1[2 * k] + c1 * w1[2 * k + 1] + b1[k];
      hid = fmaxf(hid, 0.f);
      acc += hid * w2[h * 512 + k];
    }
    table[tid] = acc;
  }
  __syncthreads();
  for (int e = tid; e < 1024; e += 256) {
    int h = e >> 8, ij = e & 255, i = ij >> 4, j = ij & 15;
    int dh = (i >> 2) - (j >> 2) + 3;
    int dw = (i & 3) - (j & 3) + 3;
    float v = table[(dh * 7 + dw) * 4 + h];
    bias_out[e] = 16.0f / (1.0f + expf(-v));
  }
  if (tid < 4) scale_out[tid] = expf(fminf(ls[tid], 4.6051701859880914f));
}

// ---------------- Kernel A2: pack fc1/fc2 weights (hi+lo) into frag order -
__global__ __launch_bounds__(256) void pack_weights_kernel(
    const float* __restrict__ fc1_w, const float* __restrict__ fc2_w,
    unsigned short* __restrict__ w1ph, unsigned short* __restrict__ w1pl,
    unsigned short* __restrict__ w2ph, unsigned short* __restrict__ w2pl) {
  int tid = blockIdx.x * 256 + threadIdx.x;  // 0..4095
  int lane = tid & 63;
  const float* src;
  unsigned short *dsth, *dstl;
  if (tid < 2048) {
    int fid = tid >> 6;  // mt*2+ks
    int m = (fid >> 1) * 16 + (lane & 15);
    int k = (fid & 1) * 32 + (lane >> 4) * 8;
    src = fc1_w + m * 64 + k;
    dsth = w1ph + tid * 8;
    dstl = w1pl + tid * 8;
  } else {
    int t2 = tid - 2048;
    int fid = t2 >> 6;  // mt2*8+ks2
    int m = (fid >> 3) * 16 + (lane & 15);
    int k = (fid & 7) * 32 + (lane >> 4) * 8;
    src = fc2_w + m * 256 + k;
    dsth = w2ph + t2 * 8;
    dstl = w2pl + t2 * 8;
  }
  float4 a = *(const float4*)src;
  float4 b = *(const float4*)(src + 4);
  float v[8] = {a.x, a.y, a.z, a.w, b.x, b.y, b.z, b.w};
  unsigned short hs[8], lls[8];
#pragma unroll
  for (int r = 0; r < 8; ++r) split1(v[r], hs[r], lls[r]);
  uint4 vh, vl;
  vh.x = (unsigned)hs[0] | ((unsigned)hs[1] << 16);
  vh.y = (unsigned)hs[2] | ((unsigned)hs[3] << 16);
  vh.z = (unsigned)hs[4] | ((unsigned)hs[5] << 16);
  vh.w = (unsigned)hs[6] | ((unsigned)hs[7] << 16);
  vl.x = (unsigned)lls[0] | ((unsigned)lls[1] << 16);
  vl.y = (unsigned)lls[2] | ((unsigned)lls[3] << 16);
  vl.z = (unsigned)lls[4] | ((unsigned)lls[5] << 16);
  vl.w = (unsigned)lls[6] | ((unsigned)lls[7] << 16);
  *(uint4*)dsth = vh;
  *(uint4*)dstl = vl;
}

// ---------------- Kernel B: window attention (MFMA QKV) + LN1 + residual -
// Verbatim R0 scalar kernel except the QKV phase: 12 M-tiles of
// [16ch x 16tok] = W(hi+lo) . X^T(hi+lo) via 6 mfma_16x16x32_bf16 each.
// A-frag: lane(col,quad) holds W[mt*16+col][quad*8+j] (+32 for ks=1).
// B-frag: lane(col,quad) holds X[token=col][ch=quad*8+j] from xw LDS.
// D-frag: lane(col,quad) reg r = out[ch=mt*16+quad*4+r][token=col],
// scattered into R0's qS/kS/vS layout with 4 scalar LDS stores.
__global__ __launch_bounds__(64) void attn_kernel(
    const float* __restrict__ x,
    const float* __restrict__ qkv_w, const float* __restrict__ qkv_b,
    const float* __restrict__ proj_w, const float* __restrict__ proj_b,
    const float* __restrict__ n1g, const float* __restrict__ n1b,
    const float* __restrict__ bias_tab, const float* __restrict__ scale_tab,
    float* __restrict__ out) {
  __shared__ float xw[16 * LDX];
  __shared__ float qS[16 * LDX];
  __shared__ float kS[4 * 16 * LDQ];
  __shared__ float vS[4 * 16 * LDQ];

  const int lane = threadIdx.x;
  const int widx = blockIdx.x;
  const int b = widx >> 12;
  const int wi = widx & 4095;
  const int wh = wi >> 6, ww = wi & 63;
  const float* xbase = x + (((size_t)(b * 256 + wh * 4) * 256) + ww * 4) * 64;

#pragma unroll
  for (int rep = 0; rep < 4; ++rep) {
    int e = rep * 64 + lane;
    int t = e >> 4, c4 = e & 15;
    int pr = t >> 2, pc = t & 3;
    float4 v = *(const float4*)(xbase + ((size_t)pr * 256 + pc) * 64 + c4 * 4);
    *(float4*)(&xw[t * LDX + c4 * 4]) = v;
  }
  __syncthreads();

  // ---- QKV via MFMA (hi+lo); replaces the scalar j-loop of R0 ----
  {
    const int col = lane & 15, quad = lane >> 4;
    bf16x8 xh[2], xl[2];
#pragma unroll
    for (int ks = 0; ks < 2; ++ks)
      splitload8(&xw[col * LDX + ks * 32 + quad * 8], xh[ks], xl[ks]);
#pragma unroll 2
    for (int mt = 0; mt < 12; ++mt) {
      const float* wrow = qkv_w + (mt * 16 + col) * 64 + quad * 8;
      bf16x8 a0h, a0l, a1h, a1l;
      splitload8(wrow, a0h, a0l);       // ks=0: k = quad*8+j
      splitload8(wrow + 32, a1h, a1l);  // ks=1: k = 32+quad*8+j
      f32x4 c = {0.f, 0.f, 0.f, 0.f};
      c = __builtin_amdgcn_mfma_f32_16x16x32_bf16(a0h, xh[0], c, 0, 0, 0);
      c = __builtin_amdgcn_mfma_f32_16x16x32_bf16(a1h, xh[1], c, 0, 0, 0);
      c = __builtin_amdgcn_mfma_f32_16x16x32_bf16(a0h, xl[0], c, 0, 0, 0);
      c = __builtin_amdgcn_mfma_f32_16x16x32_bf16(a1h, xl[1], c, 0, 0, 0);
      c = __builtin_amdgcn_mfma_f32_16x16x32_bf16(a0l, xh[0], c, 0, 0, 0);
      c = __builtin_amdgcn_mfma_f32_16x16x32_bf16(a1l, xh[1], c, 0, 0, 0);
      int which = mt >> 2, hh = mt & 3;
      float b0 = 0.f, b1 = 0.f, b2 = 0.f, b3 = 0.f;
      if (which != 1) {  // q and v bias; k bias is zeroed by the ref
        const float* bb = qkv_b + mt * 16 + quad * 4;
        b0 = bb[0]; b1 = bb[1]; b2 = bb[2]; b3 = bb[3];
      }
      float* dst = (which == 0) ? qS : ((which == 1) ? kS : vS);
      int base = (hh * 16 + col) * LDQ + quad * 4;
      dst[base + 0] = c[0] + b0;
      dst[base + 1] = c[1] + b1;
      dst[base + 2] = c[2] + b2;
      dst[base + 3] = c[3] + b3;
    }
  }
  __syncthreads();

  // ---- rest verbatim R0 ----
  const int h = lane >> 4, ti = lane & 15;
  float qreg[16];
  {
    float* qr = &qS[(h * 16 + ti) * LDQ];
    float* kr = &kS[(h * 16 + ti) * LDQ];
    float ssq = 0.f, ssk = 0.f;
#pragma unroll
    for (int d = 0; d < 16; ++d) { float v = qr[d]; qreg[d] = v; ssq += v * v; }
#pragma unroll
    for (int d = 0; d < 16; ++d) { float v = kr[d]; ssk += v * v; }
    float qsc = scale_tab[h] / fmaxf(sqrtf(ssq), 1e-12f);
    float kin = 1.0f / fmaxf(sqrtf(ssk), 1e-12f);
#pragma unroll
    for (int d = 0; d < 16; ++d) qreg[d] *= qsc;
#pragma unroll
    for (int d = 0; d < 16; ++d) kr[d] *= kin;
  }
  __syncthreads();

  {
    float p[16];
    float mx = -1e30f;
    const float* btab = bias_tab + h * 256 + ti * 16;
#pragma unroll
    for (int j = 0; j < 16; ++j) {
      const float* kr = &kS[(h * 16 + j) * LDQ];
      float s = 0.f;
#pragma unroll
      for (int d = 0; d < 16; ++d) s += qreg[d] * kr[d];
      s += btab[j];
      p[j] = s;
      mx = fmaxf(mx, s);
    }
    float sum = 0.f;
#pragma unroll
    for (int j = 0; j < 16; ++j) { float e = expf(p[j] - mx); p[j] = e; sum += e; }
    float rs = 1.0f / sum;
    float oacc[16];
#pragma unroll
    for (int d = 0; d < 16; ++d) oacc[d] = 0.f;
#pragma unroll
    for (int j = 0; j < 16; ++j) {
      const float* vr = &vS[(h * 16 + j) * LDQ];
      float pj = p[j] * rs;
#pragma unroll
      for (int d = 0; d < 16; ++d) oacc[d] += pj * vr[d];
    }
    float* os = qS;
#pragma unroll
    for (int d = 0; d < 16; ++d) os[ti * LDX + h * 16 + d] = oacc[d];
  }
  __syncthreads();

  {
    const int t = lane & 15, cg = lane >> 4;
    const float* os = qS;
    float4 orow[16];
    const float4* orp = (const float4*)(&os[t * LDX]);
#pragma unroll
    for (int c4 = 0; c4 < 16; ++c4) orow[c4] = orp[c4];
    float r2[16];
    float psum = 0.f, psq = 0.f;
#pragma unroll
    for (int m = 0; m < 16; ++m) {
      int c = cg * 16 + m;
      float acc = proj_b[c];
      const float4* wr = (const float4*)(proj_w + c * 64);
#pragma unroll
      for (int c4 = 0; c4 < 16; ++c4) {
        float4 a = orow[c4], w = wr[c4];
        acc += a.x * w.x + a.y * w.y + a.z * w.z + a.w * w.w;
      }
      r2[m] = acc;
      psum += acc;
      psq += acc * acc;
    }
    psum += __shfl_xor(psum, 16); psq += __shfl_xor(psq, 16);
    psum += __shfl_xor(psum, 32); psq += __shfl_xor(psq, 32);
    float mean = psum * (1.0f / 64.0f);
    float var = psq * (1.0f / 64.0f) - mean * mean;
    float rstd = rsqrtf(var + 1e-5f);
    int pr = t >> 2, pc = t & 3;
    float* obase = out + (((size_t)(b * 256 + wh * 4 + pr) * 256) + (ww * 4 + pc)) * 64;
#pragma unroll
    for (int m4 = 0; m4 < 4; ++m4) {
      int c = cg * 16 + m4 * 4;
      float4 res;
      float* rp = &res.x;
#pragma unroll
      for (int q = 0; q < 4; ++q) {
        float v = (r2[m4 * 4 + q] - mean) * rstd * n1g[c + q] + n1b[c + q];
        rp[q] = xw[t * LDX + c + q] + v;
      }
      *(float4*)(obase + c) = res;
    }
  }
}

// ---------------- Kernel C: MFMA MLP (hi+lo) + LN2 + residual (in-place) -
__global__ __launch_bounds__(128, 2) void mlp_mfma_kernel(
    const unsigned short* __restrict__ w1ph, const unsigned short* __restrict__ w1pl,
    const unsigned short* __restrict__ w2ph, const unsigned short* __restrict__ w2pl,
    const float* __restrict__ fc1_b, const float* __restrict__ fc2_b,
    const float* __restrict__ n2g, const float* __restrict__ n2b,
    float* __restrict__ xio) {
  __shared__ __align__(16) unsigned short Hh[2][32][264];  // stride 264: 2-way banks (free)
  __shared__ __align__(16) unsigned short Hl[2][32][264];
  const int tid = threadIdx.x;
  const int w = tid >> 6, lane = tid & 63;
  const int col = lane & 15, quad = lane >> 4;
  const size_t tbase = ((size_t)blockIdx.x * 2 + w) * 32;

  // X B-frags (hi+lo): B[k][n=token]; lane: n=col, k=quad*8+j.
  bf16x8 xh[2][2], xl[2][2];
#pragma unroll
  for (int tt = 0; tt < 2; ++tt) {
#pragma unroll
    for (int ks = 0; ks < 2; ++ks) {
      const float* p = xio + (tbase + tt * 16 + col) * 64 + ks * 32 + quad * 8;
      splitload8(p, xh[tt][ks], xl[tt][ks]);
    }
  }

  // fc1 + bias + exact-erf gelu -> Hh/Hl
#pragma unroll 2
  for (int mt = 0; mt < 16; ++mt) {
    bf16x8 a0h = *(const bf16x8*)(w1ph + (mt * 2 + 0) * 512 + lane * 8);
    bf16x8 a1h = *(const bf16x8*)(w1ph + (mt * 2 + 1) * 512 + lane * 8);
    bf16x8 a0l = *(const bf16x8*)(w1pl + (mt * 2 + 0) * 512 + lane * 8);
    bf16x8 a1l = *(const bf16x8*)(w1pl + (mt * 2 + 1) * 512 + lane * 8);
    float4 bias = *(const float4*)(fc1_b + mt * 16 + quad * 4);
    const float* bp = &bias.x;
#pragma unroll
    for (int tt = 0; tt < 2; ++tt) {
      f32x4 c = {0.f, 0.f, 0.f, 0.f};
      c = __builtin_amdgcn_mfma_f32_16x16x32_bf16(a0h, xh[tt][0], c, 0, 0, 0);
      c = __builtin_amdgcn_mfma_f32_16x16x32_bf16(a1h, xh[tt][1], c, 0, 0, 0);
      c = __builtin_amdgcn_mfma_f32_16x16x32_bf16(a0h, xl[tt][0], c, 0, 0, 0);
      c = __builtin_amdgcn_mfma_f32_16x16x32_bf16(a1h, xl[tt][1], c, 0, 0, 0);
      c = __builtin_amdgcn_mfma_f32_16x16x32_bf16(a0l, xh[tt][0], c, 0, 0, 0);
      c = __builtin_amdgcn_mfma_f32_16x16x32_bf16(a1l, xh[tt][1], c, 0, 0, 0);
      unsigned short gh[4], gl[4];
#pragma unroll
      for (int r = 0; r < 4; ++r) {
        float xv = c[r] + bp[r];
        float g = 0.5f * xv * (1.0f + erff(xv * 0.70710678118654752f));
        split1(g, gh[r], gl[r]);
      }
      uint2 pkh, pkl;
      pkh.x = (unsigned)gh[0] | ((unsigned)gh[1] << 16);
      pkh.y = (unsigned)gh[2] | ((unsigned)gh[3] << 16);
      pkl.x = (unsigned)gl[0] | ((unsigned)gl[1] << 16);
      pkl.y = (unsigned)gl[2] | ((unsigned)gl[3] << 16);
      *(uint2*)(&Hh[w][tt * 16 + col][mt * 16 + quad * 4]) = pkh;
      *(uint2*)(&Hl[w][tt * 16 + col][mt * 16 + quad * 4]) = pkl;
    }
  }
  __syncthreads();

  // fc2: loop k-tiles, B-frags from H (row-major, k-contiguous -> b128)
  f32x4 acc[2][4];
#pragma unroll
  for (int tt = 0; tt < 2; ++tt)
#pragma unroll
    for (int mt2 = 0; mt2 < 4; ++mt2)
      acc[tt][mt2] = (f32x4){0.f, 0.f, 0.f, 0.f};

#pragma unroll 2
  for (int ks = 0; ks < 8; ++ks) {
    bf16x8 bh[2], bl[2];
#pragma unroll
    for (int tt = 0; tt < 2; ++tt) {
      bh[tt] = *(const bf16x8*)(&Hh[w][tt * 16 + col][ks * 32 + quad * 8]);
      bl[tt] = *(const bf16x8*)(&Hl[w][tt * 16 + col][ks * 32 + quad * 8]);
    }
#pragma unroll
    for (int mt2 = 0; mt2 < 4; ++mt2) {
      bf16x8 ah = *(const bf16x8*)(w2ph + (mt2 * 8 + ks) * 512 + lane * 8);
      bf16x8 al = *(const bf16x8*)(w2pl + (mt2 * 8 + ks) * 512 + lane * 8);
#pragma unroll
      for (int tt = 0; tt < 2; ++tt) {
        acc[tt][mt2] = __builtin_amdgcn_mfma_f32_16x16x32_bf16(ah, bh[tt], acc[tt][mt2], 0, 0, 0);
        acc[tt][mt2] = __builtin_amdgcn_mfma_f32_16x16x32_bf16(ah, bl[tt], acc[tt][mt2], 0, 0, 0);
        acc[tt][mt2] = __builtin_amdgcn_mfma_f32_16x16x32_bf16(al, bh[tt], acc[tt][mt2], 0, 0, 0);
      }
    }
  }

  // epilogue: +fc2 bias, LN2 over 64 ch (4 quads x 16 vals), residual, store
#pragma unroll
  for (int tt = 0; tt < 2; ++tt) {
    float vals[16];
    float s = 0.f, q = 0.f;
#pragma unroll
    for (int mt2 = 0; mt2 < 4; ++mt2) {
      float4 b2 = *(const float4*)(fc2_b + mt2 * 16 + quad * 4);
      const float* b2p = &b2.x;
#pragma unroll
      for (int r = 0; r < 4; ++r) {
        float y = acc[tt][mt2][r] + b2p[r];
        vals[mt2 * 4 + r] = y;
        s += y; q += y * y;
      }
    }
    s += __shfl_xor(s, 16); q += __shfl_xor(q, 16);
    s += __shfl_xor(s, 32); q += __shfl_xor(q, 32);
    float mean = s * (1.0f / 64.0f);
    float var = q * (1.0f / 64.0f) - mean * mean;
    float rstd = rsqrtf(var + 1e-5f);
    size_t trow = (tbase + tt * 16 + col) * 64;
#pragma unroll
    for (int mt2 = 0; mt2 < 4; ++mt2) {
      int c0 = mt2 * 16 + quad * 4;
      float4 g4 = *(const float4*)(n2g + c0);
      float4 b4 = *(const float4*)(n2b + c0);
      float4 xv = *(const float4*)(xio + trow + c0);
      float4 o;
      float* op = &o.x; const float* gp = &g4.x; const float* bp = &b4.x; const float* xp = &xv.x;
#pragma unroll
      for (int r = 0; r < 4; ++r)
        op[r] = xp[r] + (vals[mt2 * 4 + r] - mean) * rstd * gp[r] + bp[r];
      *(float4*)(xio + trow + c0) = o;
    }
  }
}

extern "C" void kernel_launch(void* const* d_in, const int* in_sizes, int n_in,
                              void* d_out, int out_size, void* d_ws, size_t ws_size,
                              hipStream_t stream) {
  const float* x      = (const float*)d_in[0];
  const float* qkv_w  = (const float*)d_in[1];
  const float* qkv_b  = (const float*)d_in[2];
  const float* proj_w = (const float*)d_in[3];
  const float* proj_b = (const float*)d_in[4];
  const float* lscale = (const float*)d_in[5];
  const float* cpb_w1 = (const float*)d_in[6];
  const float* cpb_b1 = (const float*)d_in[7];
  const float* cpb_w2 = (const float*)d_in[8];
  const float* n1g    = (const float*)d_in[9];
  const float* n1b    = (const float*)d_in[10];
  const float* n2g    = (const float*)d_in[11];
  const float* n2b    = (const float*)d_in[12];
  const float* fc1_w  = (const float*)d_in[13];
  const float* fc1_b  = (const float*)d_in[14];
  const float* fc2_w  = (const float*)d_in[15];
  const float* fc2_b  = (const float*)d_in[16];
  float* out = (float*)d_out;
  float* ws  = (float*)d_ws;
  // ws layout (floats): [0..1023] bias_tab, [1024..1027] scales.
  // shorts region at ws+4096: w1ph[16384], w1pl[16384], w2ph[16384], w2pl[16384]
  // (total 147456 bytes -- proven-safe footprint)
  unsigned short* w1ph = (unsigned short*)(ws + 4096);
  unsigned short* w1pl = w1ph + 16384;
  unsigned short* w2ph = w1ph + 32768;
  unsigned short* w2pl = w1ph + 49152;

  cpb_bias_kernel<<<1, 256, 0, stream>>>(cpb_w1, cpb_b1, cpb_w2, lscale, ws, ws + 1024);
  pack_weights_kernel<<<16, 256, 0, stream>>>(fc1_w, fc2_w, w1ph, w1pl, w2ph, w2pl);
  attn_kernel<<<32768, 64, 0, stream>>>(x, qkv_w, qkv_b, proj_w, proj_b,
                                        n1g, n1b, ws, ws + 1024, out);
  mlp_mfma_kernel<<<8192, 128, 0, stream>>>(w1ph, w1pl, w2ph, w2pl,
                                            fc1_b, fc2_b, n2g, n2b, out);
}

// Round 4
// 815.541 us; speedup vs baseline: 1.8132x; 1.2067x over previous
//
#include <hip/hip_runtime.h>
#include <math.h>

// SwinTransformerBlockV2, B=8 H=W=256 C=64, 4 heads, 4x4 windows, shift 8.
// Shift 8 is a multiple of window 4 -> roll+partition == plain partition
// (permuted window ids), and mask region boundaries are window-aligned ->
// mask == 0. Hence plain per-window attention on the natural partition.
//
// R4: R3's proven structure (MFMA QKV, absmax 0.031) with the scalar proj
// also moved to MFMA double-bf16 (hi+lo): a*b ~= ah*bh + ah*bl + al*bh.
// A-frags split on the fly from fp32 weights (L1/L2-resident); attention
// core (normalize, softmax, PV) stays scalar fp32 — verbatim the passing
// version. MLP runs on MFMA hi+lo as before (proven).

#define LDX 68
#define LDQ 17

typedef __attribute__((ext_vector_type(8))) short bf16x8;
typedef __attribute__((ext_vector_type(4))) float f32x4;

__device__ inline unsigned short f2bf(float f) {
  unsigned u = __builtin_bit_cast(unsigned, f);
  u = (u + 0x7FFFu + ((u >> 16) & 1u)) >> 16;
  return (unsigned short)u;
}
__device__ inline float bf2f(unsigned short h) {
  return __builtin_bit_cast(float, ((unsigned)h) << 16);
}

// split v into hi (bf16) + lo (bf16 of residual)
__device__ inline void split1(float v, unsigned short& h, unsigned short& l) {
  h = f2bf(v);
  l = f2bf(v - bf2f(h));
}

// load 8 consecutive floats at p, split into hi/lo bf16x8 fragments
__device__ inline void splitload8(const float* p, bf16x8& h8, bf16x8& l8) {
  float4 a = *(const float4*)p;
  float4 b = *(const float4*)(p + 4);
  float v[8] = {a.x, a.y, a.z, a.w, b.x, b.y, b.z, b.w};
#pragma unroll
  for (int r = 0; r < 8; ++r) {
    unsigned short hh, ll;
    split1(v[r], hh, ll);
    h8[r] = (short)hh;
    l8[r] = (short)ll;
  }
}

// ---------------- Kernel A: CPB bias table + logit scales ----------------
__global__ __launch_bounds__(256) void cpb_bias_kernel(
    const float* __restrict__ w1, const float* __restrict__ b1,
    const float* __restrict__ w2, const float* __restrict__ ls,
    float* __restrict__ bias_out /*4*16*16*/, float* __restrict__ scale_out /*4*/) {
  __shared__ float table[196];  // [49][4]
  int tid = threadIdx.x;
  if (tid < 196) {
    int r = tid >> 2, h = tid & 3;
    int ih = r / 7, iw = r % 7;
    float t0 = (float)(ih - 3) * (8.0f / 3.0f);
    float t1 = (float)(iw - 3) * (8.0f / 3.0f);
    float c0 = copysignf(log2f(fabsf(t0) + 1.0f) * (1.0f / 3.0f), t0);
    float c1 = copysignf(log2f(fabsf(t1) + 1.0f) * (1.0f / 3.0f), t1);
    float acc = 0.f;
    for (int k = 0; k < 512; ++k) {
      float hid = c0 * w1[2 * k] + c1 * w1[2 * k + 1] + b1[k];
      hid = fmaxf(hid, 0.f);
      acc += hid * w2[h * 512 + k];
    }
    table[tid] = acc;
  }
  __syncthreads();
  for (int e = tid; e < 1024; e += 256) {
    int h = e >> 8, ij = e & 255, i = ij >> 4, j = ij & 15;
    int dh = (i >> 2) - (j >> 2) + 3;
    int dw = (i & 3) - (j & 3) + 3;
    float v = table[(dh * 7 + dw) * 4 + h];
    bias_out[e] = 16.0f / (1.0f + expf(-v));
  }
  if (tid < 4) scale_out[tid] = expf(fminf(ls[tid], 4.6051701859880914f));
}

// ---------------- Kernel A2: pack fc1/fc2 weights (hi+lo) into frag order -
__global__ __launch_bounds__(256) void pack_weights_kernel(
    const float* __restrict__ fc1_w, const float* __restrict__ fc2_w,
    unsigned short* __restrict__ w1ph, unsigned short* __restrict__ w1pl,
    unsigned short* __restrict__ w2ph, unsigned short* __restrict__ w2pl) {
  int tid = blockIdx.x * 256 + threadIdx.x;  // 0..4095
  int lane = tid & 63;
  const float* src;
  unsigned short *dsth, *dstl;
  if (tid < 2048) {
    int fid = tid >> 6;  // mt*2+ks
    int m = (fid >> 1) * 16 + (lane & 15);
    int k = (fid & 1) * 32 + (lane >> 4) * 8;
    src = fc1_w + m * 64 + k;
    dsth = w1ph + tid * 8;
    dstl = w1pl + tid * 8;
  } else {
    int t2 = tid - 2048;
    int fid = t2 >> 6;  // mt2*8+ks2
    int m = (fid >> 3) * 16 + (lane & 15);
    int k = (fid & 7) * 32 + (lane >> 4) * 8;
    src = fc2_w + m * 256 + k;
    dsth = w2ph + t2 * 8;
    dstl = w2pl + t2 * 8;
  }
  float4 a = *(const float4*)src;
  float4 b = *(const float4*)(src + 4);
  float v[8] = {a.x, a.y, a.z, a.w, b.x, b.y, b.z, b.w};
  unsigned short hs[8], lls[8];
#pragma unroll
  for (int r = 0; r < 8; ++r) split1(v[r], hs[r], lls[r]);
  uint4 vh, vl;
  vh.x = (unsigned)hs[0] | ((unsigned)hs[1] << 16);
  vh.y = (unsigned)hs[2] | ((unsigned)hs[3] << 16);
  vh.z = (unsigned)hs[4] | ((unsigned)hs[5] << 16);
  vh.w = (unsigned)hs[6] | ((unsigned)hs[7] << 16);
  vl.x = (unsigned)lls[0] | ((unsigned)lls[1] << 16);
  vl.y = (unsigned)lls[2] | ((unsigned)lls[3] << 16);
  vl.z = (unsigned)lls[4] | ((unsigned)lls[5] << 16);
  vl.w = (unsigned)lls[6] | ((unsigned)lls[7] << 16);
  *(uint4*)dsth = vh;
  *(uint4*)dstl = vl;
}

// ---------------- Kernel B: window attention (MFMA QKV+proj) + LN1 -------
// One wave per 4x4 window. QKV: 12 M-tiles of [16ch x 16tok] =
// W(hi+lo) . X^T(hi+lo) via 6 mfma_16x16x32_bf16 each (proven R3).
// proj: same pattern, 4 M-tiles over the PV output O staged in qS.
// A-frag: lane(col,quad) holds W[mt*16+col][quad*8+j] (+32 for ks=1).
// B-frag: lane(col,quad) holds X/O[token=col][ch=quad*8+j].
// D-frag: reg r = out[ch=mt*16+quad*4+r][token=col].
__global__ __launch_bounds__(64) void attn_kernel(
    const float* __restrict__ x,
    const float* __restrict__ qkv_w, const float* __restrict__ qkv_b,
    const float* __restrict__ proj_w, const float* __restrict__ proj_b,
    const float* __restrict__ n1g, const float* __restrict__ n1b,
    const float* __restrict__ bias_tab, const float* __restrict__ scale_tab,
    float* __restrict__ out) {
  __shared__ float xw[16 * LDX];
  __shared__ float qS[16 * LDX];
  __shared__ float kS[4 * 16 * LDQ];
  __shared__ float vS[4 * 16 * LDQ];

  const int lane = threadIdx.x;
  const int widx = blockIdx.x;
  const int b = widx >> 12;
  const int wi = widx & 4095;
  const int wh = wi >> 6, ww = wi & 63;
  const float* xbase = x + (((size_t)(b * 256 + wh * 4) * 256) + ww * 4) * 64;

#pragma unroll
  for (int rep = 0; rep < 4; ++rep) {
    int e = rep * 64 + lane;
    int t = e >> 4, c4 = e & 15;
    int pr = t >> 2, pc = t & 3;
    float4 v = *(const float4*)(xbase + ((size_t)pr * 256 + pc) * 64 + c4 * 4);
    *(float4*)(&xw[t * LDX + c4 * 4]) = v;
  }
  __syncthreads();

  const int col = lane & 15, quad = lane >> 4;

  // ---- QKV via MFMA (hi+lo) ----
  {
    bf16x8 xh[2], xl[2];
#pragma unroll
    for (int ks = 0; ks < 2; ++ks)
      splitload8(&xw[col * LDX + ks * 32 + quad * 8], xh[ks], xl[ks]);
#pragma unroll 2
    for (int mt = 0; mt < 12; ++mt) {
      const float* wrow = qkv_w + (mt * 16 + col) * 64 + quad * 8;
      bf16x8 a0h, a0l, a1h, a1l;
      splitload8(wrow, a0h, a0l);       // ks=0: k = quad*8+j
      splitload8(wrow + 32, a1h, a1l);  // ks=1: k = 32+quad*8+j
      f32x4 c = {0.f, 0.f, 0.f, 0.f};
      c = __builtin_amdgcn_mfma_f32_16x16x32_bf16(a0h, xh[0], c, 0, 0, 0);
      c = __builtin_amdgcn_mfma_f32_16x16x32_bf16(a1h, xh[1], c, 0, 0, 0);
      c = __builtin_amdgcn_mfma_f32_16x16x32_bf16(a0h, xl[0], c, 0, 0, 0);
      c = __builtin_amdgcn_mfma_f32_16x16x32_bf16(a1h, xl[1], c, 0, 0, 0);
      c = __builtin_amdgcn_mfma_f32_16x16x32_bf16(a0l, xh[0], c, 0, 0, 0);
      c = __builtin_amdgcn_mfma_f32_16x16x32_bf16(a1l, xh[1], c, 0, 0, 0);
      int which = mt >> 2, hh = mt & 3;
      float b0 = 0.f, b1 = 0.f, b2 = 0.f, b3 = 0.f;
      if (which != 1) {  // q and v bias; k bias is zeroed by the ref
        const float* bb = qkv_b + mt * 16 + quad * 4;
        b0 = bb[0]; b1 = bb[1]; b2 = bb[2]; b3 = bb[3];
      }
      float* dst = (which == 0) ? qS : ((which == 1) ? kS : vS);
      int base = (hh * 16 + col) * LDQ + quad * 4;
      dst[base + 0] = c[0] + b0;
      dst[base + 1] = c[1] + b1;
      dst[base + 2] = c[2] + b2;
      dst[base + 3] = c[3] + b3;
    }
  }
  __syncthreads();

  // ---- cosine-normalize (verbatim R0/R3) ----
  const int h = lane >> 4, ti = lane & 15;
  float qreg[16];
  {
    float* qr = &qS[(h * 16 + ti) * LDQ];
    float* kr = &kS[(h * 16 + ti) * LDQ];
    float ssq = 0.f, ssk = 0.f;
#pragma unroll
    for (int d = 0; d < 16; ++d) { float v = qr[d]; qreg[d] = v; ssq += v * v; }
#pragma unroll
    for (int d = 0; d < 16; ++d) { float v = kr[d]; ssk += v * v; }
    float qsc = scale_tab[h] / fmaxf(sqrtf(ssq), 1e-12f);
    float kin = 1.0f / fmaxf(sqrtf(ssk), 1e-12f);
#pragma unroll
    for (int d = 0; d < 16; ++d) qreg[d] *= qsc;
#pragma unroll
    for (int d = 0; d < 16; ++d) kr[d] *= kin;
  }
  __syncthreads();

  // ---- scores + softmax + PV (verbatim R0/R3); O -> qS rows stride LDX --
  {
    float p[16];
    float mx = -1e30f;
    const float* btab = bias_tab + h * 256 + ti * 16;
#pragma unroll
    for (int j = 0; j < 16; ++j) {
      const float* kr = &kS[(h * 16 + j) * LDQ];
      float s = 0.f;
#pragma unroll
      for (int d = 0; d < 16; ++d) s += qreg[d] * kr[d];
      s += btab[j];
      p[j] = s;
      mx = fmaxf(mx, s);
    }
    float sum = 0.f;
#pragma unroll
    for (int j = 0; j < 16; ++j) { float e = expf(p[j] - mx); p[j] = e; sum += e; }
    float rs = 1.0f / sum;
    float oacc[16];
#pragma unroll
    for (int d = 0; d < 16; ++d) oacc[d] = 0.f;
#pragma unroll
    for (int j = 0; j < 16; ++j) {
      const float* vr = &vS[(h * 16 + j) * LDQ];
      float pj = p[j] * rs;
#pragma unroll
      for (int d = 0; d < 16; ++d) oacc[d] += pj * vr[d];
    }
    float* os = qS;
#pragma unroll
    for (int d = 0; d < 16; ++d) os[ti * LDX + h * 16 + d] = oacc[d];
  }
  __syncthreads();

  // ---- proj via MFMA (hi+lo, same pattern as QKV) + LN1 + residual ----
  {
    bf16x8 oh[2], ol[2];
#pragma unroll
    for (int ks = 0; ks < 2; ++ks)
      splitload8(&qS[col * LDX + ks * 32 + quad * 8], oh[ks], ol[ks]);
    f32x4 y[4];
#pragma unroll
    for (int mt2 = 0; mt2 < 4; ++mt2) {
      const float* wrow = proj_w + (mt2 * 16 + col) * 64 + quad * 8;
      bf16x8 a0h, a0l, a1h, a1l;
      splitload8(wrow, a0h, a0l);
      splitload8(wrow + 32, a1h, a1l);
      f32x4 c = {0.f, 0.f, 0.f, 0.f};
      c = __builtin_amdgcn_mfma_f32_16x16x32_bf16(a0h, oh[0], c, 0, 0, 0);
      c = __builtin_amdgcn_mfma_f32_16x16x32_bf16(a1h, oh[1], c, 0, 0, 0);
      c = __builtin_amdgcn_mfma_f32_16x16x32_bf16(a0h, ol[0], c, 0, 0, 0);
      c = __builtin_amdgcn_mfma_f32_16x16x32_bf16(a1h, ol[1], c, 0, 0, 0);
      c = __builtin_amdgcn_mfma_f32_16x16x32_bf16(a0l, oh[0], c, 0, 0, 0);
      c = __builtin_amdgcn_mfma_f32_16x16x32_bf16(a1l, oh[1], c, 0, 0, 0);
      const float* bb = proj_b + mt2 * 16 + quad * 4;
      c[0] += bb[0]; c[1] += bb[1]; c[2] += bb[2]; c[3] += bb[3];
      y[mt2] = c;
    }
    // LN1 over 64 channels of token=col: each lane holds 16 (4 mt2 x 4 r),
    // the 4 quads hold complementary channel sets -> reduce across quads.
    float psum = 0.f, psq = 0.f;
#pragma unroll
    for (int mt2 = 0; mt2 < 4; ++mt2)
#pragma unroll
      for (int r = 0; r < 4; ++r) {
        float vv = y[mt2][r];
        psum += vv;
        psq += vv * vv;
      }
    psum += __shfl_xor(psum, 16); psq += __shfl_xor(psq, 16);
    psum += __shfl_xor(psum, 32); psq += __shfl_xor(psq, 32);
    float mean = psum * (1.0f / 64.0f);
    float var = psq * (1.0f / 64.0f) - mean * mean;
    float rstd = rsqrtf(var + 1e-5f);
    int pr = col >> 2, pc = col & 3;
    float* obase = out + (((size_t)(b * 256 + wh * 4 + pr) * 256) + (ww * 4 + pc)) * 64;
#pragma unroll
    for (int mt2 = 0; mt2 < 4; ++mt2) {
      int c0 = mt2 * 16 + quad * 4;
      float4 g4 = *(const float4*)(n1g + c0);
      float4 b4 = *(const float4*)(n1b + c0);
      float4 res;
      res.x = xw[col * LDX + c0 + 0] + (y[mt2][0] - mean) * rstd * g4.x + b4.x;
      res.y = xw[col * LDX + c0 + 1] + (y[mt2][1] - mean) * rstd * g4.y + b4.y;
      res.z = xw[col * LDX + c0 + 2] + (y[mt2][2] - mean) * rstd * g4.z + b4.z;
      res.w = xw[col * LDX + c0 + 3] + (y[mt2][3] - mean) * rstd * g4.w + b4.w;
      *(float4*)(obase + c0) = res;
    }
  }
}

// ---------------- Kernel C: MFMA MLP (hi+lo) + LN2 + residual (in-place) -
__global__ __launch_bounds__(128, 2) void mlp_mfma_kernel(
    const unsigned short* __restrict__ w1ph, const unsigned short* __restrict__ w1pl,
    const unsigned short* __restrict__ w2ph, const unsigned short* __restrict__ w2pl,
    const float* __restrict__ fc1_b, const float* __restrict__ fc2_b,
    const float* __restrict__ n2g, const float* __restrict__ n2b,
    float* __restrict__ xio) {
  __shared__ __align__(16) unsigned short Hh[2][32][264];  // stride 264: 2-way banks (free)
  __shared__ __align__(16) unsigned short Hl[2][32][264];
  const int tid = threadIdx.x;
  const int w = tid >> 6, lane = tid & 63;
  const int col = lane & 15, quad = lane >> 4;
  const size_t tbase = ((size_t)blockIdx.x * 2 + w) * 32;

  // X B-frags (hi+lo): B[k][n=token]; lane: n=col, k=quad*8+j.
  bf16x8 xh[2][2], xl[2][2];
#pragma unroll
  for (int tt = 0; tt < 2; ++tt) {
#pragma unroll
    for (int ks = 0; ks < 2; ++ks) {
      const float* p = xio + (tbase + tt * 16 + col) * 64 + ks * 32 + quad * 8;
      splitload8(p, xh[tt][ks], xl[tt][ks]);
    }
  }

  // fc1 + bias + exact-erf gelu -> Hh/Hl
#pragma unroll 2
  for (int mt = 0; mt < 16; ++mt) {
    bf16x8 a0h = *(const bf16x8*)(w1ph + (mt * 2 + 0) * 512 + lane * 8);
    bf16x8 a1h = *(const bf16x8*)(w1ph + (mt * 2 + 1) * 512 + lane * 8);
    bf16x8 a0l = *(const bf16x8*)(w1pl + (mt * 2 + 0) * 512 + lane * 8);
    bf16x8 a1l = *(const bf16x8*)(w1pl + (mt * 2 + 1) * 512 + lane * 8);
    float4 bias = *(const float4*)(fc1_b + mt * 16 + quad * 4);
    const float* bp = &bias.x;
#pragma unroll
    for (int tt = 0; tt < 2; ++tt) {
      f32x4 c = {0.f, 0.f, 0.f, 0.f};
      c = __builtin_amdgcn_mfma_f32_16x16x32_bf16(a0h, xh[tt][0], c, 0, 0, 0);
      c = __builtin_amdgcn_mfma_f32_16x16x32_bf16(a1h, xh[tt][1], c, 0, 0, 0);
      c = __builtin_amdgcn_mfma_f32_16x16x32_bf16(a0h, xl[tt][0], c, 0, 0, 0);
      c = __builtin_amdgcn_mfma_f32_16x16x32_bf16(a1h, xl[tt][1], c, 0, 0, 0);
      c = __builtin_amdgcn_mfma_f32_16x16x32_bf16(a0l, xh[tt][0], c, 0, 0, 0);
      c = __builtin_amdgcn_mfma_f32_16x16x32_bf16(a1l, xh[tt][1], c, 0, 0, 0);
      unsigned short gh[4], gl[4];
#pragma unroll
      for (int r = 0; r < 4; ++r) {
        float xv = c[r] + bp[r];
        float g = 0.5f * xv * (1.0f + erff(xv * 0.70710678118654752f));
        split1(g, gh[r], gl[r]);
      }
      uint2 pkh, pkl;
      pkh.x = (unsigned)gh[0] | ((unsigned)gh[1] << 16);
      pkh.y = (unsigned)gh[2] | ((unsigned)gh[3] << 16);
      pkl.x = (unsigned)gl[0] | ((unsigned)gl[1] << 16);
      pkl.y = (unsigned)gl[2] | ((unsigned)gl[3] << 16);
      *(uint2*)(&Hh[w][tt * 16 + col][mt * 16 + quad * 4]) = pkh;
      *(uint2*)(&Hl[w][tt * 16 + col][mt * 16 + quad * 4]) = pkl;
    }
  }
  __syncthreads();

  // fc2: loop k-tiles, B-frags from H (row-major, k-contiguous -> b128)
  f32x4 acc[2][4];
#pragma unroll
  for (int tt = 0; tt < 2; ++tt)
#pragma unroll
    for (int mt2 = 0; mt2 < 4; ++mt2)
      acc[tt][mt2] = (f32x4){0.f, 0.f, 0.f, 0.f};

#pragma unroll 2
  for (int ks = 0; ks < 8; ++ks) {
    bf16x8 bh[2], bl[2];
#pragma unroll
    for (int tt = 0; tt < 2; ++tt) {
      bh[tt] = *(const bf16x8*)(&Hh[w][tt * 16 + col][ks * 32 + quad * 8]);
      bl[tt] = *(const bf16x8*)(&Hl[w][tt * 16 + col][ks * 32 + quad * 8]);
    }
#pragma unroll
    for (int mt2 = 0; mt2 < 4; ++mt2) {
      bf16x8 ah = *(const bf16x8*)(w2ph + (mt2 * 8 + ks) * 512 + lane * 8);
      bf16x8 al = *(const bf16x8*)(w2pl + (mt2 * 8 + ks) * 512 + lane * 8);
#pragma unroll
      for (int tt = 0; tt < 2; ++tt) {
        acc[tt][mt2] = __builtin_amdgcn_mfma_f32_16x16x32_bf16(ah, bh[tt], acc[tt][mt2], 0, 0, 0);
        acc[tt][mt2] = __builtin_amdgcn_mfma_f32_16x16x32_bf16(ah, bl[tt], acc[tt][mt2], 0, 0, 0);
        acc[tt][mt2] = __builtin_amdgcn_mfma_f32_16x16x32_bf16(al, bh[tt], acc[tt][mt2], 0, 0, 0);
      }
    }
  }

  // epilogue: +fc2 bias, LN2 over 64 ch (4 quads x 16 vals), residual, store
#pragma unroll
  for (int tt = 0; tt < 2; ++tt) {
    float vals[16];
    float s = 0.f, q = 0.f;
#pragma unroll
    for (int mt2 = 0; mt2 < 4; ++mt2) {
      float4 b2 = *(const float4*)(fc2_b + mt2 * 16 + quad * 4);
      const float* b2p = &b2.x;
#pragma unroll
      for (int r = 0; r < 4; ++r) {
        float y = acc[tt][mt2][r] + b2p[r];
        vals[mt2 * 4 + r] = y;
        s += y; q += y * y;
      }
    }
    s += __shfl_xor(s, 16); q += __shfl_xor(q, 16);
    s += __shfl_xor(s, 32); q += __shfl_xor(q, 32);
    float mean = s * (1.0f / 64.0f);
    float var = q * (1.0f / 64.0f) - mean * mean;
    float rstd = rsqrtf(var + 1e-5f);
    size_t trow = (tbase + tt * 16 + col) * 64;
#pragma unroll
    for (int mt2 = 0; mt2 < 4; ++mt2) {
      int c0 = mt2 * 16 + quad * 4;
      float4 g4 = *(const float4*)(n2g + c0);
      float4 b4 = *(const float4*)(n2b + c0);
      float4 xv = *(const float4*)(xio + trow + c0);
      float4 o;
      float* op = &o.x; const float* gp = &g4.x; const float* bp = &b4.x; const float* xp = &xv.x;
#pragma unroll
      for (int r = 0; r < 4; ++r)
        op[r] = xp[r] + (vals[mt2 * 4 + r] - mean) * rstd * gp[r] + bp[r];
      *(float4*)(xio + trow + c0) = o;
    }
  }
}

extern "C" void kernel_launch(void* const* d_in, const int* in_sizes, int n_in,
                              void* d_out, int out_size, void* d_ws, size_t ws_size,
                              hipStream_t stream) {
  const float* x      = (const float*)d_in[0];
  const float* qkv_w  = (const float*)d_in[1];
  const float* qkv_b  = (const float*)d_in[2];
  const float* proj_w = (const float*)d_in[3];
  const float* proj_b = (const float*)d_in[4];
  const float* lscale = (const float*)d_in[5];
  const float* cpb_w1 = (const float*)d_in[6];
  const float* cpb_b1 = (const float*)d_in[7];
  const float* cpb_w2 = (const float*)d_in[8];
  const float* n1g    = (const float*)d_in[9];
  const float* n1b    = (const float*)d_in[10];
  const float* n2g    = (const float*)d_in[11];
  const float* n2b    = (const float*)d_in[12];
  const float* fc1_w  = (const float*)d_in[13];
  const float* fc1_b  = (const float*)d_in[14];
  const float* fc2_w  = (const float*)d_in[15];
  const float* fc2_b  = (const float*)d_in[16];
  float* out = (float*)d_out;
  float* ws  = (float*)d_ws;
  // ws layout (floats): [0..1023] bias_tab, [1024..1027] scales.
  // shorts region at ws+4096: w1ph[16384], w1pl[16384], w2ph[16384], w2pl[16384]
  // (total 147456 bytes -- proven-safe footprint)
  unsigned short* w1ph = (unsigned short*)(ws + 4096);
  unsigned short* w1pl = w1ph + 16384;
  unsigned short* w2ph = w1ph + 32768;
  unsigned short* w2pl = w1ph + 49152;

  cpb_bias_kernel<<<1, 256, 0, stream>>>(cpb_w1, cpb_b1, cpb_w2, lscale, ws, ws + 1024);
  pack_weights_kernel<<<16, 256, 0, stream>>>(fc1_w, fc2_w, w1ph, w1pl, w2ph, w2pl);
  attn_kernel<<<32768, 64, 0, stream>>>(x, qkv_w, qkv_b, proj_w, proj_b,
                                        n1g, n1b, ws, ws + 1024, out);
  mlp_mfma_kernel<<<8192, 128, 0, stream>>>(w1ph, w1pl, w2ph, w2pl,
                                            fc1_b, fc2_b, n2g, n2b, out);
}